// Round 14
// baseline (1292.976 us; speedup 1.0000x reference)
//
#include <hip/hip_runtime.h>
#include <hip/hip_bf16.h>

#define NB 8
#define NP 8192
#define NC 6
#define NG 512
#define GS 32

#define CENTER_OFF (NB * NG * GS * NC)        /* 786432 */
#define IDX_OFF    (CENTER_OFF + NB * NG * 3) /* 798720 */

// Dtypes (validated R6-R13): d_in[0] f32, d_out f32; _rn math in the
// reference's association order. fps = (max dist, tie -> min idx);
// knn = (min d2, tie -> min idx) == lax.top_k stable order. absmax 0.0.
// R14: fps interleaves TWO batches per block (4 blocks x 512 thr) — one
// barrier serves two FPS instances; independent A/B chains fill stalls.
// Winner gather from global (L2-resident). knn untouched (R8-validated).

#define DPP_MAX_U32(v, ctrl)                                               \
  {                                                                        \
    unsigned _m = (unsigned)__builtin_amdgcn_update_dpp(                   \
        (int)(v), (int)(v), (ctrl), 0xf, 0xf, false);                      \
    (v) = (_m > (v)) ? _m : (v);                                           \
  }

// ---------------------------------------------------------------------------
// Kernel 1: FPS, dual-batch. 512 thr (8 waves), 16 pts/thread/batch.
// Per effective iter: f32 fmax tree -> cmp-mask+ctz first-j (min idx among
// maxima; replaces 128-cyc serial scan, same semantics) -> DPP u32 max +
// ballot arg-resolve (validated) -> lane0 ds_write. Both batches, then ONE
// parity barrier, both 8-partial u64 reduces, both global gathers, both
// _rn min-updates.
// ---------------------------------------------------------------------------
__global__ __launch_bounds__(512) void fps_kernel(
    const float* __restrict__ xyz, float* __restrict__ out,
    int* __restrict__ cidx)
{
  __shared__ unsigned long long kpA[2][8], kpB[2][8];
  __shared__ int selA[NG], selB[NG];

  const int pair = blockIdx.x;               // 0..3
  const int bA = pair * 2, bB = bA + 1;
  const int tid = threadIdx.x;
  const int lane = tid & 63;
  const int wave = tid >> 6;
  const float* baseA = xyz + (size_t)bA * NP * NC;
  const float* baseB = xyz + (size_t)bB * NP * NC;

  float pxA[16], pyA[16], pzA[16], dvA[16];
  float pxB[16], pyB[16], pzB[16], dvB[16];
#pragma unroll
  for (int j = 0; j < 16; ++j) {
    const int p = tid + (j << 9);
    pxA[j] = baseA[p * 6 + 0];
    pyA[j] = baseA[p * 6 + 1];
    pzA[j] = baseA[p * 6 + 2];
    pxB[j] = baseB[p * 6 + 0];
    pyB[j] = baseB[p * 6 + 1];
    pzB[j] = baseB[p * 6 + 2];
  }
  if (tid == 0) { selA[0] = 0; selB[0] = 0; }

  float cxA = baseA[0], cyA = baseA[1], czA = baseA[2];
  float cxB = baseB[0], cyB = baseB[1], czB = baseB[2];

#pragma unroll
  for (int j = 0; j < 16; ++j) {
    {
      const float dx = __fsub_rn(pxA[j], cxA);
      const float dy = __fsub_rn(pyA[j], cyA);
      const float dz = __fsub_rn(pzA[j], czA);
      dvA[j] = __fadd_rn(
          __fadd_rn(__fmul_rn(dx, dx), __fmul_rn(dy, dy)), __fmul_rn(dz, dz));
    }
    {
      const float dx = __fsub_rn(pxB[j], cxB);
      const float dy = __fsub_rn(pyB[j], cyB);
      const float dz = __fsub_rn(pzB[j], czB);
      dvB[j] = __fadd_rn(
          __fadd_rn(__fmul_rn(dx, dx), __fmul_rn(dy, dy)), __fmul_rn(dz, dz));
    }
  }

  for (int it = 1; it < NG; ++it) {
    const int pb = it & 1;

    // ---- phase 1, batch A: local argmax key -> kpA[pb][wave] ----
    {
      float t[8];
#pragma unroll
      for (int j = 0; j < 8; ++j) t[j] = fmaxf(dvA[j], dvA[j + 8]);
#pragma unroll
      for (int s = 4; s; s >>= 1)
#pragma unroll
        for (int j = 0; j < s; ++j) t[j] = fmaxf(t[j], t[j + s]);
      const float m = t[0];
      unsigned mask = 0;
#pragma unroll
      for (int j = 0; j < 16; ++j)
        mask |= (dvA[j] == m) ? (1u << j) : 0u;
      const int jj = __builtin_ctz(mask);       // first j == min point idx
      const unsigned lo = (unsigned)(NP - 1 - tid - (jj << 9));

      const unsigned sv = __float_as_uint(m);   // dv>=0: u32 order == f32
      unsigned r = sv;
      DPP_MAX_U32(r, 0x111); DPP_MAX_U32(r, 0x112); DPP_MAX_U32(r, 0x114);
      DPP_MAX_U32(r, 0x118); DPP_MAX_U32(r, 0x142); DPP_MAX_U32(r, 0x143);
      const unsigned smax = (unsigned)__builtin_amdgcn_readlane((int)r, 63);

      const unsigned long long mk = __ballot(sv == smax);
      unsigned wlo;
      if (mk & (mk - 1)) {        // lane tie: max lo = min point idx
        unsigned long long mm = mk; unsigned best = 0;
        while (mm) {
          const int l = __builtin_ctzll(mm);
          const unsigned c = (unsigned)__builtin_amdgcn_readlane((int)lo, l);
          if (c > best) best = c;
          mm &= mm - 1;
        }
        wlo = best;
      } else {
        wlo = (unsigned)__builtin_amdgcn_readlane((int)lo,
                                                  __builtin_ctzll(mk));
      }
      if (lane == 0) kpA[pb][wave] = ((unsigned long long)smax << 32) | wlo;
    }

    // ---- phase 1, batch B ----
    {
      float t[8];
#pragma unroll
      for (int j = 0; j < 8; ++j) t[j] = fmaxf(dvB[j], dvB[j + 8]);
#pragma unroll
      for (int s = 4; s; s >>= 1)
#pragma unroll
        for (int j = 0; j < s; ++j) t[j] = fmaxf(t[j], t[j + s]);
      const float m = t[0];
      unsigned mask = 0;
#pragma unroll
      for (int j = 0; j < 16; ++j)
        mask |= (dvB[j] == m) ? (1u << j) : 0u;
      const int jj = __builtin_ctz(mask);
      const unsigned lo = (unsigned)(NP - 1 - tid - (jj << 9));

      const unsigned sv = __float_as_uint(m);
      unsigned r = sv;
      DPP_MAX_U32(r, 0x111); DPP_MAX_U32(r, 0x112); DPP_MAX_U32(r, 0x114);
      DPP_MAX_U32(r, 0x118); DPP_MAX_U32(r, 0x142); DPP_MAX_U32(r, 0x143);
      const unsigned smax = (unsigned)__builtin_amdgcn_readlane((int)r, 63);

      const unsigned long long mk = __ballot(sv == smax);
      unsigned wlo;
      if (mk & (mk - 1)) {
        unsigned long long mm = mk; unsigned best = 0;
        while (mm) {
          const int l = __builtin_ctzll(mm);
          const unsigned c = (unsigned)__builtin_amdgcn_readlane((int)lo, l);
          if (c > best) best = c;
          mm &= mm - 1;
        }
        wlo = best;
      } else {
        wlo = (unsigned)__builtin_amdgcn_readlane((int)lo,
                                                  __builtin_ctzll(mk));
      }
      if (lane == 0) kpB[pb][wave] = ((unsigned long long)smax << 32) | wlo;
    }

    __syncthreads();

    // ---- phase 2: reduce 8 partials per batch (broadcast LDS reads) ----
    const unsigned long long* ka = kpA[pb];
    unsigned long long a0 = ka[0] > ka[1] ? ka[0] : ka[1];
    unsigned long long a1 = ka[2] > ka[3] ? ka[2] : ka[3];
    unsigned long long a2 = ka[4] > ka[5] ? ka[4] : ka[5];
    unsigned long long a3 = ka[6] > ka[7] ? ka[6] : ka[7];
    a0 = a0 > a1 ? a0 : a1;
    a2 = a2 > a3 ? a2 : a3;
    a0 = a0 > a2 ? a0 : a2;
    const int giA = (NP - 1) - (int)(unsigned)(a0 & 0xFFFFFFFFu);

    const unsigned long long* kb = kpB[pb];
    unsigned long long b0 = kb[0] > kb[1] ? kb[0] : kb[1];
    unsigned long long b1 = kb[2] > kb[3] ? kb[2] : kb[3];
    unsigned long long b2 = kb[4] > kb[5] ? kb[4] : kb[5];
    unsigned long long b3 = kb[6] > kb[7] ? kb[6] : kb[7];
    b0 = b0 > b1 ? b0 : b1;
    b2 = b2 > b3 ? b2 : b3;
    b0 = b0 > b2 ? b0 : b2;
    const int giB = (NP - 1) - (int)(unsigned)(b0 & 0xFFFFFFFFu);

    if (tid == 0) { selA[it] = giA; selB[it] = giB; }

    // ---- gather winner coords from global (L2-resident) ----
    const float* pA = baseA + (size_t)giA * 6;
    const float* pB = baseB + (size_t)giB * 6;
    const float nxA = pA[0], nyA = pA[1], nzA = pA[2];
    const float nxB = pB[0], nyB = pB[1], nzB = pB[2];
    cxA = nxA; cyA = nyA; czA = nzA;
    cxB = nxB; cyB = nyB; czB = nzB;

    // ---- min-update both batches ----
#pragma unroll
    for (int j = 0; j < 16; ++j) {
      {
        const float dx = __fsub_rn(pxA[j], cxA);
        const float dy = __fsub_rn(pyA[j], cyA);
        const float dz = __fsub_rn(pzA[j], czA);
        const float d = __fadd_rn(
            __fadd_rn(__fmul_rn(dx, dx), __fmul_rn(dy, dy)),
            __fmul_rn(dz, dz));
        dvA[j] = fminf(dvA[j], d);
      }
      {
        const float dx = __fsub_rn(pxB[j], cxB);
        const float dy = __fsub_rn(pyB[j], cyB);
        const float dz = __fsub_rn(pzB[j], czB);
        const float d = __fadd_rn(
            __fadd_rn(__fmul_rn(dx, dx), __fmul_rn(dy, dy)),
            __fmul_rn(dz, dz));
        dvB[j] = fminf(dvB[j], d);
      }
    }
  }
  __syncthreads();

  // epilogue: 512 threads = NG groups, both batches, coords from global
  {
    const int pA = selA[tid];
    const size_t cbA = (size_t)(bA * NG + tid) * 3;
    out[CENTER_OFF + cbA + 0] = baseA[pA * 6 + 0];
    out[CENTER_OFF + cbA + 1] = baseA[pA * 6 + 1];
    out[CENTER_OFF + cbA + 2] = baseA[pA * 6 + 2];
    cidx[bA * NG + tid] = pA;

    const int pB = selB[tid];
    const size_t cbB = (size_t)(bB * NG + tid) * 3;
    out[CENTER_OFF + cbB + 0] = baseB[pB * 6 + 0];
    out[CENTER_OFF + cbB + 1] = baseB[pB * 6 + 1];
    out[CENTER_OFF + cbB + 2] = baseB[pB * 6 + 2];
    cidx[bB * NG + tid] = pB;
  }
}

// ---------------------------------------------------------------------------
// Kernel 2: 32-NN — R8-validated version, UNTOUCHED (absmax 0.0).
// ---------------------------------------------------------------------------
__global__ __launch_bounds__(256) void knn_kernel(
    const float* __restrict__ xyz, float* __restrict__ out,
    const int* __restrict__ cidx)
{
  __shared__ unsigned long long kpart[2][4];

  const int bg = blockIdx.x;
  const int b = bg >> 9;
  const int tid = threadIdx.x;
  const int lane = tid & 63;
  const int wave = tid >> 6;
  const float* base = xyz + (size_t)b * NP * NC;

  const int pc = cidx[bg] & (NP - 1);  // clamp: fault-proof under any state
  const float cx = base[pc * 6 + 0];
  const float cy = base[pc * 6 + 1];
  const float cz = base[pc * 6 + 2];
  const float cc = __fadd_rn(
      __fadd_rn(__fmul_rn(cx, cx), __fmul_rn(cy, cy)), __fmul_rn(cz, cz));

  float dreg[32];
  float lv = __builtin_inff();
  int   li = 0x7fffffff;
#pragma unroll
  for (int j = 0; j < 32; ++j) {
    const int p = tid + (j << 8);
    const float x = base[p * 6 + 0];
    const float y = base[p * 6 + 1];
    const float z = base[p * 6 + 2];
    const float xx = __fadd_rn(
        __fadd_rn(__fmul_rn(x, x), __fmul_rn(y, y)), __fmul_rn(z, z));
    const float dot = __fadd_rn(
        __fadd_rn(__fmul_rn(cx, x), __fmul_rn(cy, y)), __fmul_rn(cz, z));
    const float d2 = __fsub_rn(__fadd_rn(cc, xx), __fmul_rn(2.0f, dot));
    dreg[j] = d2;
    if (d2 < lv) { lv = d2; li = p; }  // strict <: first min (lowest index)
  }

  int myp = 0;
  for (int k = 0; k < GS; ++k) {
    unsigned u = __float_as_uint(lv);
    u ^= ((unsigned)((int)u >> 31)) | 0x80000000u;
    unsigned long long key = ((unsigned long long)u << 32) | (unsigned)li;
#pragma unroll
    for (int off = 32; off; off >>= 1) {
      const unsigned long long ok = __shfl_xor(key, off);
      if (ok < key) key = ok;
    }
    const int pb = k & 1;
    if (lane == 0) kpart[pb][wave] = key;
    __syncthreads();

    unsigned long long g = kpart[pb][lane & 3];
#pragma unroll
    for (int off = 1; off < 4; off <<= 1) {
      const unsigned long long og = __shfl_xor(g, off);
      if (og < g) g = og;
    }
    const int p = (int)(unsigned)(g & 0xFFFFFFFFu);
    if (tid == k) myp = p;

    if ((p & 255) == tid) {
      const int wj = p >> 8;
      lv = __builtin_inff(); li = 0x7fffffff;
#pragma unroll
      for (int j = 0; j < 32; ++j) {
        if (j == wj) dreg[j] = __builtin_inff();
        if (dreg[j] < lv) { lv = dreg[j]; li = tid + (j << 8); }
      }
    }
  }

  if (tid < GS) {
    const int p = myp & (NP - 1);  // in-bounds by construction
    const float v0 = base[p * 6 + 0];
    const float v1 = base[p * 6 + 1];
    const float v2 = base[p * 6 + 2];
    const size_t ob = ((size_t)bg * GS + tid) * 6;
    out[ob + 0] = __fsub_rn(v0, cx);
    out[ob + 1] = __fsub_rn(v1, cy);
    out[ob + 2] = __fsub_rn(v2, cz);
    out[ob + 3] = base[p * 6 + 3];  // extras: raw f32 passthrough
    out[ob + 4] = base[p * 6 + 4];
    out[ob + 5] = base[p * 6 + 5];
    out[IDX_OFF + (size_t)bg * GS + tid] = (float)p;  // idx as f32 value
  }
}

extern "C" void kernel_launch(void* const* d_in, const int* in_sizes, int n_in,
                              void* d_out, int out_size, void* d_ws,
                              size_t ws_size, hipStream_t stream)
{
  const float* xyz = (const float*)d_in[0];
  float* out = (float*)d_out;
  int* cidx = (int*)d_ws;  // NB*NG ints = 16 KiB scratch

  hipLaunchKernelGGL(fps_kernel, dim3(NB / 2), dim3(512), 0, stream,
                     xyz, out, cidx);
  hipLaunchKernelGGL(knn_kernel, dim3(NB * NG), dim3(256), 0, stream,
                     xyz, out, cidx);
}

// Round 15
// 684.751 us; speedup vs baseline: 1.8882x; 1.8882x over previous
//
#include <hip/hip_runtime.h>
#include <hip/hip_bf16.h>

#define NB 8
#define NP 8192
#define NC 6
#define NG 512
#define GS 32

#define CENTER_OFF (NB * NG * GS * NC)        /* 786432 */
#define IDX_OFF    (CENTER_OFF + NB * NG * 3) /* 798720 */

// Dtypes (validated R6-R14): d_in[0] f32, d_out f32; _rn math in the
// reference's association order. fps = (max dist, tie -> min idx);
// knn = (min d2, tie -> min idx) == lax.top_k stable order.
// R15 = bank best-validated parts: fps from R12 (256 thr, 32 pts/thread,
// f32 maxtree, LDS float4 mirror; 490 us, selection-exact per R11/R12
// invariance) with the R14-validated mask+ctz first-j; knn from R8 (204 us,
// absmax 0.0). R14 lesson: >180 f32 state/thread at 512 thr -> scratch
// spill (VGPR_Count 80, fps 1093 us) — dual-batch abandoned.

#define DPP_MAX_U32(v, ctrl)                                               \
  {                                                                        \
    unsigned _m = (unsigned)__builtin_amdgcn_update_dpp(                   \
        (int)(v), (int)(v), (ctrl), 0xf, 0xf, false);                      \
    (v) = (_m > (v)) ? _m : (v);                                           \
  }

// ---------------------------------------------------------------------------
// Kernel 1: FPS. 256 thr (4 waves, 1/SIMD), 32 pts/thread.
// Per iter: f32 fmax tree (31 ops) -> cmp-mask+ctz first-j (min idx among
// per-thread maxima) -> DPP u32 max + ballot arg-resolve -> lane0 ds_write
// -> ONE parity barrier -> 4-partial u64 register tree -> float4 mir gather
// -> _rn min-update. No global ops in the loop.
// ---------------------------------------------------------------------------
__global__ __launch_bounds__(256) void fps_kernel(
    const float* __restrict__ xyz, float* __restrict__ out,
    int* __restrict__ cidx)
{
  __shared__ float4 mir[NP];                    // 128 KB point mirror
  __shared__ unsigned long long kpart[2][4];
  __shared__ int sel[NG];

  const int b = blockIdx.x;
  const int tid = threadIdx.x;
  const int lane = tid & 63;
  const int wave = tid >> 6;
  const float* base = xyz + (size_t)b * NP * NC;

  float px[32], py[32], pz[32], dv[32];
#pragma unroll
  for (int j = 0; j < 32; ++j) {
    const int p = tid + (j << 8);
    px[j] = base[p * 6 + 0];
    py[j] = base[p * 6 + 1];
    pz[j] = base[p * 6 + 2];
    mir[p] = make_float4(px[j], py[j], pz[j], 0.0f);
  }
  if (tid == 0) sel[0] = 0;
  __syncthreads();

  float4 c0 = mir[0];
  float cx = c0.x, cy = c0.y, cz = c0.z;

#pragma unroll
  for (int j = 0; j < 32; ++j) {
    const float dx = __fsub_rn(px[j], cx);
    const float dy = __fsub_rn(py[j], cy);
    const float dz = __fsub_rn(pz[j], cz);
    dv[j] = __fadd_rn(
        __fadd_rn(__fmul_rn(dx, dx), __fmul_rn(dy, dy)), __fmul_rn(dz, dz));
  }

  for (int it = 1; it < NG; ++it) {
    // f32 max tree (fmaxf returns an input bit-exactly; dv >= 0, no NaN)
    float t[16];
#pragma unroll
    for (int j = 0; j < 16; ++j) t[j] = fmaxf(dv[j], dv[j + 16]);
#pragma unroll
    for (int s = 8; s; s >>= 1)
#pragma unroll
      for (int j = 0; j < s; ++j) t[j] = fmaxf(t[j], t[j + s]);
    const float m = t[0];
    // first j with dv[j]==m -> min point idx (mask+ctz, R14-validated)
    unsigned mask = 0;
#pragma unroll
    for (int j = 0; j < 32; ++j)
      mask |= (dv[j] == m) ? (1u << j) : 0u;
    const int jj = __builtin_ctz(mask);
    const unsigned lo = (unsigned)(NP - 1 - tid - (jj << 8));  // 8191 - p

    // wave max of m's bits (dv>=0: u32 order == f32 order)
    const unsigned sv = __float_as_uint(m);
    unsigned r = sv;
    DPP_MAX_U32(r, 0x111); DPP_MAX_U32(r, 0x112); DPP_MAX_U32(r, 0x114);
    DPP_MAX_U32(r, 0x118); DPP_MAX_U32(r, 0x142); DPP_MAX_U32(r, 0x143);
    const unsigned smax = (unsigned)__builtin_amdgcn_readlane((int)r, 63);

    const unsigned long long mk = __ballot(sv == smax);
    unsigned wlo;
    if (mk & (mk - 1)) {          // lane tie: max lo = min point idx
      unsigned long long mm = mk; unsigned best = 0;
      while (mm) {
        const int l = __builtin_ctzll(mm);
        const unsigned c = (unsigned)__builtin_amdgcn_readlane((int)lo, l);
        if (c > best) best = c;
        mm &= mm - 1;
      }
      wlo = best;
    } else {
      wlo = (unsigned)__builtin_amdgcn_readlane((int)lo, __builtin_ctzll(mk));
    }

    const int pb = it & 1;
    if (lane == 0)
      kpart[pb][wave] = ((unsigned long long)smax << 32) | wlo;
    __syncthreads();

    const unsigned long long* kp = kpart[pb];
    unsigned long long g0 = kp[0] > kp[1] ? kp[0] : kp[1];
    unsigned long long g1 = kp[2] > kp[3] ? kp[2] : kp[3];
    g0 = g0 > g1 ? g0 : g1;
    const int gi = (NP - 1) - (int)(unsigned)(g0 & 0xFFFFFFFFu);
    if (tid == 0) sel[it] = gi;

    const float4 c = mir[gi];     // one ds_read_b128 broadcast
    cx = c.x; cy = c.y; cz = c.z;

#pragma unroll
    for (int j = 0; j < 32; ++j) {
      const float dx = __fsub_rn(px[j], cx);
      const float dy = __fsub_rn(py[j], cy);
      const float dz = __fsub_rn(pz[j], cz);
      const float d = __fadd_rn(
          __fadd_rn(__fmul_rn(dx, dx), __fmul_rn(dy, dy)), __fmul_rn(dz, dz));
      dv[j] = fminf(dv[j], d);
    }
  }
  __syncthreads();

  for (int g = tid; g < NG; g += 256) {
    const int p = sel[g];
    const float4 c = mir[p];
    const size_t cb = (size_t)(b * NG + g) * 3;
    out[CENTER_OFF + cb + 0] = c.x;
    out[CENTER_OFF + cb + 1] = c.y;
    out[CENTER_OFF + cb + 2] = c.z;
    cidx[b * NG + g] = p;
  }
}

// ---------------------------------------------------------------------------
// Kernel 2: 32-NN — R8-validated version, UNTOUCHED (absmax 0.0).
// ---------------------------------------------------------------------------
__global__ __launch_bounds__(256) void knn_kernel(
    const float* __restrict__ xyz, float* __restrict__ out,
    const int* __restrict__ cidx)
{
  __shared__ unsigned long long kpart[2][4];

  const int bg = blockIdx.x;
  const int b = bg >> 9;
  const int tid = threadIdx.x;
  const int lane = tid & 63;
  const int wave = tid >> 6;
  const float* base = xyz + (size_t)b * NP * NC;

  const int pc = cidx[bg] & (NP - 1);  // clamp: fault-proof under any state
  const float cx = base[pc * 6 + 0];
  const float cy = base[pc * 6 + 1];
  const float cz = base[pc * 6 + 2];
  const float cc = __fadd_rn(
      __fadd_rn(__fmul_rn(cx, cx), __fmul_rn(cy, cy)), __fmul_rn(cz, cz));

  float dreg[32];
  float lv = __builtin_inff();
  int   li = 0x7fffffff;
#pragma unroll
  for (int j = 0; j < 32; ++j) {
    const int p = tid + (j << 8);
    const float x = base[p * 6 + 0];
    const float y = base[p * 6 + 1];
    const float z = base[p * 6 + 2];
    const float xx = __fadd_rn(
        __fadd_rn(__fmul_rn(x, x), __fmul_rn(y, y)), __fmul_rn(z, z));
    const float dot = __fadd_rn(
        __fadd_rn(__fmul_rn(cx, x), __fmul_rn(cy, y)), __fmul_rn(cz, z));
    const float d2 = __fsub_rn(__fadd_rn(cc, xx), __fmul_rn(2.0f, dot));
    dreg[j] = d2;
    if (d2 < lv) { lv = d2; li = p; }  // strict <: first min (lowest index)
  }

  int myp = 0;
  for (int k = 0; k < GS; ++k) {
    unsigned u = __float_as_uint(lv);
    u ^= ((unsigned)((int)u >> 31)) | 0x80000000u;
    unsigned long long key = ((unsigned long long)u << 32) | (unsigned)li;
#pragma unroll
    for (int off = 32; off; off >>= 1) {
      const unsigned long long ok = __shfl_xor(key, off);
      if (ok < key) key = ok;
    }
    const int pb = k & 1;
    if (lane == 0) kpart[pb][wave] = key;
    __syncthreads();

    unsigned long long g = kpart[pb][lane & 3];
#pragma unroll
    for (int off = 1; off < 4; off <<= 1) {
      const unsigned long long og = __shfl_xor(g, off);
      if (og < g) g = og;
    }
    const int p = (int)(unsigned)(g & 0xFFFFFFFFu);
    if (tid == k) myp = p;

    if ((p & 255) == tid) {
      const int wj = p >> 8;
      lv = __builtin_inff(); li = 0x7fffffff;
#pragma unroll
      for (int j = 0; j < 32; ++j) {
        if (j == wj) dreg[j] = __builtin_inff();
        if (dreg[j] < lv) { lv = dreg[j]; li = tid + (j << 8); }
      }
    }
  }

  if (tid < GS) {
    const int p = myp & (NP - 1);  // in-bounds by construction
    const float v0 = base[p * 6 + 0];
    const float v1 = base[p * 6 + 1];
    const float v2 = base[p * 6 + 2];
    const size_t ob = ((size_t)bg * GS + tid) * 6;
    out[ob + 0] = __fsub_rn(v0, cx);
    out[ob + 1] = __fsub_rn(v1, cy);
    out[ob + 2] = __fsub_rn(v2, cz);
    out[ob + 3] = base[p * 6 + 3];  // extras: raw f32 passthrough
    out[ob + 4] = base[p * 6 + 4];
    out[ob + 5] = base[p * 6 + 5];
    out[IDX_OFF + (size_t)bg * GS + tid] = (float)p;  // idx as f32 value
  }
}

extern "C" void kernel_launch(void* const* d_in, const int* in_sizes, int n_in,
                              void* d_out, int out_size, void* d_ws,
                              size_t ws_size, hipStream_t stream)
{
  const float* xyz = (const float*)d_in[0];
  float* out = (float*)d_out;
  int* cidx = (int*)d_ws;  // NB*NG ints = 16 KiB scratch

  hipLaunchKernelGGL(fps_kernel, dim3(NB), dim3(256), 0, stream,
                     xyz, out, cidx);
  hipLaunchKernelGGL(knn_kernel, dim3(NB * NG), dim3(256), 0, stream,
                     xyz, out, cidx);
}

// Round 16
// 669.691 us; speedup vs baseline: 1.9307x; 1.0225x over previous
//
#include <hip/hip_runtime.h>
#include <hip/hip_bf16.h>

#define NB 8
#define NP 8192
#define NC 6
#define NG 512
#define GS 32

#define CENTER_OFF (NB * NG * GS * NC)        /* 786432 */
#define IDX_OFF    (CENTER_OFF + NB * NG * 3) /* 798720 */

// Dtypes (validated R6-R15): d_in[0] f32, d_out f32; _rn math in the
// reference's association order. fps = (max dist, tie -> min idx);
// knn = (min d2, tie -> min idx) == lax.top_k stable order.
// R16: fps unchanged (488 us, R15-validated). knn keeps R8 topology but the
// owner rescan becomes a tournament-of-4: flipped-u32 keys du[32], 4 group
// minima; removal rescans one group of 8 (~25 inst vs 128). Selection order
// provably identical (monotone flip; ascending-group strict < == first-min).

#define DPP_MAX_U32(v, ctrl)                                               \
  {                                                                        \
    unsigned _m = (unsigned)__builtin_amdgcn_update_dpp(                   \
        (int)(v), (int)(v), (ctrl), 0xf, 0xf, false);                      \
    (v) = (_m > (v)) ? _m : (v);                                           \
  }

// ---------------------------------------------------------------------------
// Kernel 1: FPS — UNCHANGED from R15 (488 us, absmax 0.0).
// 256 thr (4 waves, 1/SIMD), 32 pts/thread; f32 maxtree + mask/ctz first-j;
// DPP u32 max + ballot arg-resolve; ONE parity barrier; float4 LDS mirror.
// ---------------------------------------------------------------------------
__global__ __launch_bounds__(256) void fps_kernel(
    const float* __restrict__ xyz, float* __restrict__ out,
    int* __restrict__ cidx)
{
  __shared__ float4 mir[NP];                    // 128 KB point mirror
  __shared__ unsigned long long kpart[2][4];
  __shared__ int sel[NG];

  const int b = blockIdx.x;
  const int tid = threadIdx.x;
  const int lane = tid & 63;
  const int wave = tid >> 6;
  const float* base = xyz + (size_t)b * NP * NC;

  float px[32], py[32], pz[32], dv[32];
#pragma unroll
  for (int j = 0; j < 32; ++j) {
    const int p = tid + (j << 8);
    px[j] = base[p * 6 + 0];
    py[j] = base[p * 6 + 1];
    pz[j] = base[p * 6 + 2];
    mir[p] = make_float4(px[j], py[j], pz[j], 0.0f);
  }
  if (tid == 0) sel[0] = 0;
  __syncthreads();

  float4 c0 = mir[0];
  float cx = c0.x, cy = c0.y, cz = c0.z;

#pragma unroll
  for (int j = 0; j < 32; ++j) {
    const float dx = __fsub_rn(px[j], cx);
    const float dy = __fsub_rn(py[j], cy);
    const float dz = __fsub_rn(pz[j], cz);
    dv[j] = __fadd_rn(
        __fadd_rn(__fmul_rn(dx, dx), __fmul_rn(dy, dy)), __fmul_rn(dz, dz));
  }

  for (int it = 1; it < NG; ++it) {
    float t[16];
#pragma unroll
    for (int j = 0; j < 16; ++j) t[j] = fmaxf(dv[j], dv[j + 16]);
#pragma unroll
    for (int s = 8; s; s >>= 1)
#pragma unroll
      for (int j = 0; j < s; ++j) t[j] = fmaxf(t[j], t[j + s]);
    const float m = t[0];
    unsigned mask = 0;
#pragma unroll
    for (int j = 0; j < 32; ++j)
      mask |= (dv[j] == m) ? (1u << j) : 0u;
    const int jj = __builtin_ctz(mask);
    const unsigned lo = (unsigned)(NP - 1 - tid - (jj << 8));  // 8191 - p

    const unsigned sv = __float_as_uint(m);
    unsigned r = sv;
    DPP_MAX_U32(r, 0x111); DPP_MAX_U32(r, 0x112); DPP_MAX_U32(r, 0x114);
    DPP_MAX_U32(r, 0x118); DPP_MAX_U32(r, 0x142); DPP_MAX_U32(r, 0x143);
    const unsigned smax = (unsigned)__builtin_amdgcn_readlane((int)r, 63);

    const unsigned long long mk = __ballot(sv == smax);
    unsigned wlo;
    if (mk & (mk - 1)) {          // lane tie: max lo = min point idx
      unsigned long long mm = mk; unsigned best = 0;
      while (mm) {
        const int l = __builtin_ctzll(mm);
        const unsigned c = (unsigned)__builtin_amdgcn_readlane((int)lo, l);
        if (c > best) best = c;
        mm &= mm - 1;
      }
      wlo = best;
    } else {
      wlo = (unsigned)__builtin_amdgcn_readlane((int)lo, __builtin_ctzll(mk));
    }

    const int pb = it & 1;
    if (lane == 0)
      kpart[pb][wave] = ((unsigned long long)smax << 32) | wlo;
    __syncthreads();

    const unsigned long long* kp = kpart[pb];
    unsigned long long g0 = kp[0] > kp[1] ? kp[0] : kp[1];
    unsigned long long g1 = kp[2] > kp[3] ? kp[2] : kp[3];
    g0 = g0 > g1 ? g0 : g1;
    const int gi = (NP - 1) - (int)(unsigned)(g0 & 0xFFFFFFFFu);
    if (tid == 0) sel[it] = gi;

    const float4 c = mir[gi];     // one ds_read_b128 broadcast
    cx = c.x; cy = c.y; cz = c.z;

#pragma unroll
    for (int j = 0; j < 32; ++j) {
      const float dx = __fsub_rn(px[j], cx);
      const float dy = __fsub_rn(py[j], cy);
      const float dz = __fsub_rn(pz[j], cz);
      const float d = __fadd_rn(
          __fadd_rn(__fmul_rn(dx, dx), __fmul_rn(dy, dy)), __fmul_rn(dz, dz));
      dv[j] = fminf(dv[j], d);
    }
  }
  __syncthreads();

  for (int g = tid; g < NG; g += 256) {
    const int p = sel[g];
    const float4 c = mir[p];
    const size_t cb = (size_t)(b * NG + g) * 3;
    out[CENTER_OFF + cb + 0] = c.x;
    out[CENTER_OFF + cb + 1] = c.y;
    out[CENTER_OFF + cb + 2] = c.z;
    cidx[b * NG + g] = p;
  }
}

// ---------------------------------------------------------------------------
// Kernel 2: 32-NN. R8 topology + tournament-of-4 local minima (u32 domain).
// Per round: 3-cmp lane key -> 6-step u64 shfl min -> lane0 ds_write -> ONE
// parity barrier -> 4-partial register tree (broadcast LDS reads) -> owner
// invalidates one slot + rescans one group of 8.
// ---------------------------------------------------------------------------
__global__ __launch_bounds__(256) void knn_kernel(
    const float* __restrict__ xyz, float* __restrict__ out,
    const int* __restrict__ cidx)
{
  __shared__ unsigned long long kpart[2][4];

  const int bg = blockIdx.x;
  const int b = bg >> 9;
  const int tid = threadIdx.x;
  const int lane = tid & 63;
  const int wave = tid >> 6;
  const float* base = xyz + (size_t)b * NP * NC;

  const int pc = cidx[bg] & (NP - 1);  // clamp: fault-proof under any state
  const float cx = base[pc * 6 + 0];
  const float cy = base[pc * 6 + 1];
  const float cz = base[pc * 6 + 2];
  const float cc = __fadd_rn(
      __fadd_rn(__fmul_rn(cx, cx), __fmul_rn(cy, cy)), __fmul_rn(cz, cz));

  // flipped-u32 keys (monotone in d2; 0xFFFFFFFF unreachable by real values)
  unsigned du[32];
#pragma unroll
  for (int j = 0; j < 32; ++j) {
    const int p = tid + (j << 8);
    const float x = base[p * 6 + 0];
    const float y = base[p * 6 + 1];
    const float z = base[p * 6 + 2];
    const float xx = __fadd_rn(
        __fadd_rn(__fmul_rn(x, x), __fmul_rn(y, y)), __fmul_rn(z, z));
    const float dot = __fadd_rn(
        __fadd_rn(__fmul_rn(cx, x), __fmul_rn(cy, y)), __fmul_rn(cz, z));
    const float d2 = __fsub_rn(__fadd_rn(cc, xx), __fmul_rn(2.0f, dot));
    unsigned u = __float_as_uint(d2);
    u ^= ((unsigned)((int)u >> 31)) | 0x80000000u;
    du[j] = u;
  }

  // tournament state: min value/j per group of 8 (ascending scan, strict <
  // == first-min == lowest point index, same as R8's serial rescan)
  unsigned gvu[4]; int gj[4];
#pragma unroll
  for (int g = 0; g < 4; ++g) {
    unsigned bv = du[8 * g]; int bj = 8 * g;
#pragma unroll
    for (int rr = 1; rr < 8; ++rr)
      if (du[8 * g + rr] < bv) { bv = du[8 * g + rr]; bj = 8 * g + rr; }
    gvu[g] = bv; gj[g] = bj;
  }

  int myp = 0;
  for (int k = 0; k < GS; ++k) {
    // lane key: merge 4 group minima (ascending g, strict < -> lowest idx)
    unsigned bv = gvu[0]; int bj = gj[0];
#pragma unroll
    for (int g = 1; g < 4; ++g)
      if (gvu[g] < bv) { bv = gvu[g]; bj = gj[g]; }
    unsigned long long key =
        ((unsigned long long)bv << 32) | (unsigned)(tid + (bj << 8));
#pragma unroll
    for (int off = 32; off; off >>= 1) {
      const unsigned long long ok = __shfl_xor(key, off);
      if (ok < key) key = ok;
    }
    const int pb = k & 1;
    if (lane == 0) kpart[pb][wave] = key;
    __syncthreads();

    const unsigned long long* kp = kpart[pb];
    unsigned long long g0 = kp[0] < kp[1] ? kp[0] : kp[1];
    unsigned long long g1 = kp[2] < kp[3] ? kp[2] : kp[3];
    g0 = g0 < g1 ? g0 : g1;
    const int p = (int)(unsigned)(g0 & 0xFFFFFFFFu);  // winner point index
    if (tid == k) myp = p;

    // owner: invalidate winner slot, rescan ONLY its group of 8
    if ((p & 255) == tid) {
      const int wj = p >> 8;
      const int gg = wj >> 3;
#pragma unroll
      for (int g = 0; g < 4; ++g)
        if (g == gg) {
#pragma unroll
          for (int rr = 0; rr < 8; ++rr)
            if (8 * g + rr == wj) du[8 * g + rr] = 0xFFFFFFFFu;
          unsigned bv2 = du[8 * g]; int bj2 = 8 * g;
#pragma unroll
          for (int rr = 1; rr < 8; ++rr)
            if (du[8 * g + rr] < bv2) { bv2 = du[8 * g + rr]; bj2 = 8 * g + rr; }
          gvu[g] = bv2; gj[g] = bj2;
        }
    }
  }

  if (tid < GS) {
    const int p = myp & (NP - 1);  // in-bounds by construction
    const float v0 = base[p * 6 + 0];
    const float v1 = base[p * 6 + 1];
    const float v2 = base[p * 6 + 2];
    const size_t ob = ((size_t)bg * GS + tid) * 6;
    out[ob + 0] = __fsub_rn(v0, cx);
    out[ob + 1] = __fsub_rn(v1, cy);
    out[ob + 2] = __fsub_rn(v2, cz);
    out[ob + 3] = base[p * 6 + 3];  // extras: raw f32 passthrough
    out[ob + 4] = base[p * 6 + 4];
    out[ob + 5] = base[p * 6 + 5];
    out[IDX_OFF + (size_t)bg * GS + tid] = (float)p;  // idx as f32 value
  }
}

extern "C" void kernel_launch(void* const* d_in, const int* in_sizes, int n_in,
                              void* d_out, int out_size, void* d_ws,
                              size_t ws_size, hipStream_t stream)
{
  const float* xyz = (const float*)d_in[0];
  float* out = (float*)d_out;
  int* cidx = (int*)d_ws;  // NB*NG ints = 16 KiB scratch

  hipLaunchKernelGGL(fps_kernel, dim3(NB), dim3(256), 0, stream,
                     xyz, out, cidx);
  hipLaunchKernelGGL(knn_kernel, dim3(NB * NG), dim3(256), 0, stream,
                     xyz, out, cidx);
}